// Round 8
// baseline (659.391 us; speedup 1.0000x reference)
//
#include <hip/hip_runtime.h>
#include <math.h>

constexpr int N_NODES = 500000;
constexpr int N_EDGES = 8000000;
constexpr int IN_DIM = 10, HID_DIM = 35, OUT_DIM = 2;

constexpr int BUCKET_BITS = 11;                       // 2048 dst-nodes per bucket
constexpr int BNODES = 1 << BUCKET_BITS;              // 2048
constexpr int NB = (N_NODES + BNODES - 1) / BNODES;   // 245 buckets
constexpr int NBP = 256;                              // padded

constexpr int CHUNK_SHIFT = 15;                       // 32768 src-nodes per chunk (1.3 MB of x)
constexpr int NCHUNK = 16;                            // (500000-1)>>15 = 15 -> chunks 0..15
constexpr int NBIN2 = BNODES * NCHUNK;                // 32768 (dl, chunk) bins per bucket

constexpr int PART_TPB = 1024;
constexpr int EPT = 16;
constexpr int TILE = PART_TPB * EPT;                  // 16384
constexpr int NTILES = (N_EDGES + TILE - 1) / TILE;   // 489

// ---------------- zero bucket counters ----------------
__global__ void zero_small_kernel(unsigned* __restrict__ bcount) {
    bcount[threadIdx.x] = 0u;
}

// ---------------- histogram: edges per dst-bucket (245 bins) ----------------
__global__ void hist_kernel(const int* __restrict__ dst, unsigned* __restrict__ bcount, int E) {
    __shared__ unsigned h[NBP];
    h[threadIdx.x] = 0u;
    __syncthreads();
    int stride = gridDim.x * blockDim.x;
    for (int e = blockIdx.x * blockDim.x + threadIdx.x; e < E; e += stride)
        atomicAdd(&h[dst[e] >> BUCKET_BITS], 1u);
    __syncthreads();
    if (h[threadIdx.x]) atomicAdd(&bcount[threadIdx.x], h[threadIdx.x]);
}

// ---------------- exclusive scan of bucket counts (1 block, 256) -------------
__global__ void scan_kernel(const unsigned* __restrict__ bcount,
                            unsigned* __restrict__ bbase, unsigned* __restrict__ bcursor,
                            unsigned* __restrict__ rowstart) {
    __shared__ unsigned s[NBP];
    int t = threadIdx.x;
    unsigned v = bcount[t];
    s[t] = v; __syncthreads();
    for (int off = 1; off < NBP; off <<= 1) {
        unsigned a = (t >= off) ? s[t - off] : 0u;
        __syncthreads();
        s[t] += a;
        __syncthreads();
    }
    bbase[t] = s[t] - v;  bcursor[t] = s[t] - v;   // bins >= NB are zero => bbase[NB..] = E
    if (t == 0) { bbase[NBP] = (unsigned)N_EDGES; rowstart[N_NODES] = (unsigned)N_EDGES; }
}

// ---------------- partition: pack (src<<11 | dst&2047) grouped by bucket ------
__global__ __launch_bounds__(PART_TPB) void partition_kernel(
        const int* __restrict__ src, const int* __restrict__ dst,
        unsigned* __restrict__ bcursor, unsigned* __restrict__ packed, int E) {
    __shared__ unsigned h[NBP], base[NBP], c2[NBP];
    int t = threadIdx.x;
    for (int k = t; k < NBP; k += PART_TPB) { h[k] = 0u; c2[k] = 0u; }
    __syncthreads();
    int tile0 = blockIdx.x * TILE;
    int d[EPT];
    #pragma unroll
    for (int q = 0; q < EPT; ++q) {
        int e = tile0 + q * PART_TPB + t;
        d[q] = (e < E) ? dst[e] : -1;
        if (d[q] >= 0) atomicAdd(&h[d[q] >> BUCKET_BITS], 1u);
    }
    __syncthreads();
    for (int k = t; k < NBP; k += PART_TPB)
        if (h[k]) base[k] = atomicAdd(&bcursor[k], h[k]);
    __syncthreads();
    #pragma unroll
    for (int q = 0; q < EPT; ++q) {
        int e = tile0 + q * PART_TPB + t;
        if (d[q] >= 0) {
            int b = d[q] >> BUCKET_BITS;
            unsigned pos = base[b] + atomicAdd(&c2[b], 1u);
            packed[pos] = ((unsigned)src[e] << BUCKET_BITS) | (unsigned)(d[q] & (BNODES - 1));
        }
    }
}

// ---------------- per-bucket CSR build, rows sorted by src-chunk --------------
// Bins = (dst_local, src_chunk): cnt2[2048*16] (128 KB LDS). Hist -> scan ->
// scatter. Also emits rowstart, dinv, and prescales x by dinv in place.
__global__ __launch_bounds__(1024) void csrbuild_kernel(
        const unsigned* __restrict__ packed, const unsigned* __restrict__ bbase,
        unsigned* __restrict__ rowstart, int* __restrict__ csr,
        float* __restrict__ dinv, float* __restrict__ x, int N) {
    __shared__ unsigned cnt2[NBIN2];   // 128 KB
    __shared__ unsigned stmp[1024];
    int b = blockIdx.x, t = threadIdx.x;
    #pragma unroll
    for (int k = 0; k < NBIN2 / 1024; ++k) cnt2[t + k * 1024] = 0u;
    __syncthreads();
    unsigned base = bbase[b], end = bbase[b + 1];
    for (unsigned e = base + t; e < end; e += 1024) {
        unsigned p = packed[e];
        // bin = dl*16 + chunk(src);  chunk(src) = src>>15 = p>>(11+15)
        unsigned bin = ((p & (BNODES - 1)) << 4) | (p >> (BUCKET_BITS + CHUNK_SHIFT));
        atomicAdd(&cnt2[bin], 1u);
    }
    __syncthreads();
    // thread t owns bins [32t, 32t+32) = dst rows {2t, 2t+1}
    unsigned loc[32];
    unsigned deg0 = 0, deg1 = 0;
    #pragma unroll
    for (int k = 0; k < 16; ++k) { loc[k] = cnt2[32 * t + k]; deg0 += loc[k]; }
    #pragma unroll
    for (int k = 16; k < 32; ++k) { loc[k] = cnt2[32 * t + k]; deg1 += loc[k]; }
    unsigned tsum = deg0 + deg1;
    stmp[t] = tsum; __syncthreads();
    for (int off = 1; off < 1024; off <<= 1) {
        unsigned a = (t >= off) ? stmp[t - off] : 0u;
        __syncthreads();
        stmp[t] += a;
        __syncthreads();
    }
    unsigned run = stmp[t] - tsum;  // exclusive prefix within bucket
    #pragma unroll
    for (int k = 0; k < 32; ++k) { cnt2[32 * t + k] = run; run += loc[k]; }
    // rowstart + dinv + x-prescale for this thread's two nodes
    int node0 = b << BUCKET_BITS;
    int i0 = node0 + 2 * t, i1 = i0 + 1;
    if (i0 < N) {
        rowstart[i0] = base + cnt2[32 * t];
        float di = rsqrtf((float)deg0 + 1.0f);  // +1 = self-loop
        dinv[i0] = di;
        float2* xr = reinterpret_cast<float2*>(x + (size_t)i0 * IN_DIM);
        #pragma unroll
        for (int q = 0; q < 5; ++q) { float2 v = xr[q]; v.x *= di; v.y *= di; xr[q] = v; }
    }
    if (i1 < N) {
        rowstart[i1] = base + cnt2[32 * t + 16];
        float di = rsqrtf((float)deg1 + 1.0f);
        dinv[i1] = di;
        float2* xr = reinterpret_cast<float2*>(x + (size_t)i1 * IN_DIM);
        #pragma unroll
        for (int q = 0; q < 5; ++q) { float2 v = xr[q]; v.x *= di; v.y *= di; xr[q] = v; }
    }
    __syncthreads();
    // scatter src into csr grouped by (dl, chunk)  -> rows sorted by chunk
    for (unsigned e = base + t; e < end; e += 1024) {
        unsigned p = packed[e];
        unsigned bin = ((p & (BNODES - 1)) << 4) | (p >> (BUCKET_BITS + CHUNK_SHIFT));
        unsigned pos = base + atomicAdd(&cnt2[bin], 1u);
        csr[pos] = (int)(p >> BUCKET_BITS);
    }
}

// ---------------- layer-1: chunk-swept register gather + fused MLP ------------
// All ~500K threads co-resident (2 blocks/CU via launch_bounds): each sweeps
// src-chunks 0..15 in soft lockstep -> current 1.3 MB x-slice is L2-resident.
__global__ __launch_bounds__(1024, 8) void gather1_kernel(
        const int* __restrict__ csr, const unsigned* __restrict__ rowstart,
        const float* __restrict__ xs, const float* __restrict__ dinv,
        const float* __restrict__ W1, const float* __restrict__ b1,
        const float* __restrict__ W2, float2* __restrict__ ts, int N) {
    __shared__ float sW1[IN_DIM * HID_DIM];
    __shared__ float sb1[HID_DIM];
    __shared__ float sW2[HID_DIM * OUT_DIM];
    int t = threadIdx.x;
    for (int k = t; k < IN_DIM * HID_DIM; k += 1024) sW1[k] = W1[k];
    if (t < HID_DIM) sb1[t] = b1[t];
    if (t < HID_DIM * OUT_DIM) sW2[t] = W2[t];
    __syncthreads();

    int i = blockIdx.x * 1024 + t;
    if (i >= N) return;
    unsigned ptr = rowstart[i], end = rowstart[i + 1];
    float v[IN_DIM];
    const float2* xi = reinterpret_cast<const float2*>(xs + (size_t)i * IN_DIM);
    #pragma unroll
    for (int q = 0; q < 5; ++q) { float2 u = xi[q]; v[2*q] = u.x; v[2*q+1] = u.y; }
    #pragma unroll 1
    for (int c = 0; c < NCHUNK; ++c) {
        while (ptr < end) {
            int s = csr[ptr];
            if ((s >> CHUNK_SHIFT) != c) break;   // row sorted by chunk
            const float2* xr = reinterpret_cast<const float2*>(xs + (size_t)s * IN_DIM);
            #pragma unroll
            for (int q = 0; q < 5; ++q) { float2 u = xr[q]; v[2*q] += u.x; v[2*q+1] += u.y; }
            ++ptr;
        }
    }
    float di = dinv[i];
    #pragma unroll
    for (int k = 0; k < IN_DIM; ++k) v[k] *= di;
    float t0 = 0.0f, t1 = 0.0f;
    #pragma unroll
    for (int j = 0; j < HID_DIM; ++j) {
        float hh = sb1[j];
        #pragma unroll
        for (int q = 0; q < IN_DIM; ++q) hh = fmaf(v[q], sW1[q * HID_DIM + j], hh);
        hh = fmaxf(hh, 0.0f);
        t0 = fmaf(hh, sW2[2*j+0], t0);
        t1 = fmaf(hh, sW2[2*j+1], t1);
    }
    ts[i] = make_float2(t0 * di, t1 * di);
}

// ---------------- layer-2: register gather + bias + log_softmax ---------------
__global__ __launch_bounds__(256) void gather2_kernel(
        const int* __restrict__ csr, const unsigned* __restrict__ rowstart,
        const float2* __restrict__ ts, const float* __restrict__ dinv,
        const float* __restrict__ b2, float2* __restrict__ out, int N) {
    int i = blockIdx.x * 256 + threadIdx.x;
    if (i >= N) return;
    unsigned beg = rowstart[i], end = rowstart[i + 1];
    float2 acc = ts[i];  // self-loop (already carries dinv[i] factor)
    unsigned e = beg;
    int s = (e < end) ? csr[e] : 0;
    while (e < end) {
        int sn = (e + 1 < end) ? csr[e + 1] : 0;  // read-ahead
        float2 tv = ts[s];
        acc.x += tv.x; acc.y += tv.y;
        s = sn; ++e;
    }
    float di = dinv[i];
    float a0 = di * acc.x + b2[0];
    float a1 = di * acc.y + b2[1];
    float m = fmaxf(a0, a1);
    float lse = m + logf(expf(a0 - m) + expf(a1 - m));
    out[i] = make_float2(a0 - lse, a1 - lse);
}

extern "C" void kernel_launch(void* const* d_in, const int* in_sizes, int n_in,
                              void* d_out, int out_size, void* d_ws, size_t ws_size,
                              hipStream_t stream) {
    float* x        = (float*)d_in[0];       // prescaled in place (harness restores)
    const int* ei   = (const int*)d_in[1];   // [2, E]: src row then dst row
    const float* W1 = (const float*)d_in[2];
    const float* b1 = (const float*)d_in[3];
    const float* W2 = (const float*)d_in[4];
    const float* b2 = (const float*)d_in[5];
    float2* out = (float2*)d_out;

    const int* src = ei;
    const int* dst = ei + N_EDGES;

    // workspace (4B elems):
    // bcount[256] | bbase[257] | bcursor[256] | rowstart[N+1] | dinv[N] | ts[2N]
    // | packed[E] | csr[E]      ~= 72 MB
    unsigned* bcount   = (unsigned*)d_ws;
    unsigned* bbase    = bcount + NBP;
    unsigned* bcursor  = bbase + NBP + 1;
    unsigned* rowstart = bcursor + NBP;
    float*    dinv     = (float*)(rowstart + N_NODES + 1);
    float2*   ts       = (float2*)(dinv + N_NODES);
    unsigned* packed   = (unsigned*)(ts + N_NODES);
    int*      csr      = (int*)(packed + N_EDGES);

    zero_small_kernel<<<1, NBP, 0, stream>>>(bcount);
    hist_kernel<<<1024, NBP, 0, stream>>>(dst, bcount, N_EDGES);
    scan_kernel<<<1, NBP, 0, stream>>>(bcount, bbase, bcursor, rowstart);
    partition_kernel<<<NTILES, PART_TPB, 0, stream>>>(src, dst, bcursor, packed, N_EDGES);
    csrbuild_kernel<<<NB, 1024, 0, stream>>>(packed, bbase, rowstart, csr, dinv, x, N_NODES);
    gather1_kernel<<<(N_NODES + 1023) / 1024, 1024, 0, stream>>>(csr, rowstart, x, dinv, W1, b1, W2, ts, N_NODES);
    gather2_kernel<<<(N_NODES + 255) / 256, 256, 0, stream>>>(csr, rowstart, ts, dinv, b2, out, N_NODES);
}

// Round 9
// 570.956 us; speedup vs baseline: 1.1549x; 1.1549x over previous
//
#include <hip/hip_runtime.h>
#include <math.h>

constexpr int N_NODES = 500000;
constexpr int N_EDGES = 8000000;
constexpr int IN_DIM = 10, HID_DIM = 35, OUT_DIM = 2;

constexpr int BUCKET_BITS = 11;                       // 2048 dst-nodes per bucket
constexpr int BNODES = 1 << BUCKET_BITS;              // 2048
constexpr int NB = (N_NODES + BNODES - 1) / BNODES;   // 245 buckets
constexpr int NBP = 256;                              // padded

constexpr int PART_TPB = 1024;
constexpr int EPT = 16;
constexpr int TILE = PART_TPB * EPT;                  // 16384
constexpr int NTILES = (N_EDGES + TILE - 1) / TILE;   // 489

// ---------------- zero bucket counters ----------------
__global__ void zero_small_kernel(unsigned* __restrict__ bcount) {
    bcount[threadIdx.x] = 0u;
}

// ---------------- histogram: edges per dst-bucket (245 bins), int4 loads ------
__global__ void hist_kernel(const int4* __restrict__ dst4, unsigned* __restrict__ bcount,
                            int E4) {
    __shared__ unsigned h[NBP];
    h[threadIdx.x] = 0u;
    __syncthreads();
    int stride = gridDim.x * blockDim.x;
    for (int e = blockIdx.x * blockDim.x + threadIdx.x; e < E4; e += stride) {
        int4 v = dst4[e];
        atomicAdd(&h[v.x >> BUCKET_BITS], 1u);
        atomicAdd(&h[v.y >> BUCKET_BITS], 1u);
        atomicAdd(&h[v.z >> BUCKET_BITS], 1u);
        atomicAdd(&h[v.w >> BUCKET_BITS], 1u);
    }
    __syncthreads();
    if (h[threadIdx.x]) atomicAdd(&bcount[threadIdx.x], h[threadIdx.x]);
}

// ---------------- exclusive scan of bucket counts (1 block, 256) -------------
__global__ void scan_kernel(const unsigned* __restrict__ bcount,
                            unsigned* __restrict__ bbase, unsigned* __restrict__ bcursor,
                            unsigned* __restrict__ rowstart) {
    __shared__ unsigned s[NBP];
    int t = threadIdx.x;
    unsigned v = bcount[t];
    s[t] = v; __syncthreads();
    for (int off = 1; off < NBP; off <<= 1) {
        unsigned a = (t >= off) ? s[t - off] : 0u;
        __syncthreads();
        s[t] += a;
        __syncthreads();
    }
    bbase[t] = s[t] - v;  bcursor[t] = s[t] - v;
    if (t == 0) { bbase[NBP] = (unsigned)N_EDGES; rowstart[N_NODES] = (unsigned)N_EDGES; }
}

// ---------------- partition: pack (src<<11 | dst&2047) grouped by bucket ------
__global__ __launch_bounds__(PART_TPB) void partition_kernel(
        const int* __restrict__ src, const int* __restrict__ dst,
        unsigned* __restrict__ bcursor, unsigned* __restrict__ packed, int E) {
    __shared__ unsigned h[NBP], base[NBP], c2[NBP];
    int t = threadIdx.x;
    for (int k = t; k < NBP; k += PART_TPB) { h[k] = 0u; c2[k] = 0u; }
    __syncthreads();
    int tile0 = blockIdx.x * TILE;
    int d[EPT];
    #pragma unroll
    for (int q = 0; q < EPT; ++q) {
        int e = tile0 + q * PART_TPB + t;
        d[q] = (e < E) ? dst[e] : -1;
        if (d[q] >= 0) atomicAdd(&h[d[q] >> BUCKET_BITS], 1u);
    }
    __syncthreads();
    for (int k = t; k < NBP; k += PART_TPB)
        if (h[k]) base[k] = atomicAdd(&bcursor[k], h[k]);
    __syncthreads();
    #pragma unroll
    for (int q = 0; q < EPT; ++q) {
        int e = tile0 + q * PART_TPB + t;
        if (d[q] >= 0) {
            int b = d[q] >> BUCKET_BITS;
            unsigned pos = base[b] + atomicAdd(&c2[b], 1u);
            packed[pos] = ((unsigned)src[e] << BUCKET_BITS) | (unsigned)(d[q] & (BNODES - 1));
        }
    }
}

// ---------------- per-bucket CSR build + rowstart + dinv ----------------------
__global__ __launch_bounds__(1024) void csrbuild_kernel(
        const unsigned* __restrict__ packed, const unsigned* __restrict__ bbase,
        unsigned* __restrict__ rowstart, int* __restrict__ csr,
        float* __restrict__ dinv, int N) {
    __shared__ unsigned cnt[BNODES];   // degrees
    __shared__ unsigned pref[BNODES];  // prefix -> cursor
    __shared__ unsigned stmp[1024];
    int b = blockIdx.x, t = threadIdx.x;
    cnt[t] = 0u; cnt[t + 1024] = 0u;
    __syncthreads();
    unsigned base = bbase[b], end = bbase[b + 1];
    for (unsigned e = base + t; e < end; e += 1024)
        atomicAdd(&cnt[packed[e] & (BNODES - 1)], 1u);
    __syncthreads();
    unsigned a0 = cnt[2 * t], a1 = cnt[2 * t + 1];
    unsigned tsum = a0 + a1;
    stmp[t] = tsum; __syncthreads();
    for (int off = 1; off < 1024; off <<= 1) {
        unsigned a = (t >= off) ? stmp[t - off] : 0u;
        __syncthreads();
        stmp[t] += a;
        __syncthreads();
    }
    unsigned pre = stmp[t] - tsum;
    pref[2 * t] = pre; pref[2 * t + 1] = pre + a0;
    __syncthreads();
    int node0 = b << BUCKET_BITS;
    for (int k = t; k < BNODES; k += 1024) {
        int i = node0 + k;
        if (i < N) {
            rowstart[i] = base + pref[k];
            dinv[i] = rsqrtf((float)cnt[k] + 1.0f);  // +1 = self-loop
        }
    }
    __syncthreads();
    for (unsigned e = base + t; e < end; e += 1024) {
        unsigned p = packed[e];
        unsigned dl = p & (BNODES - 1);
        unsigned pos = base + atomicAdd(&pref[dl], 1u);
        csr[pos] = (int)(p >> BUCKET_BITS);
    }
}

// ---------------- padded, prescaled x copy: xp[i] = 64B row = dinv[i]*x[i] ----
// Full-line writes (pad zeroed) -> no read-modify-write allocate.
__global__ void padx_kernel(const float* __restrict__ x, const float* __restrict__ dinv,
                            float* __restrict__ xp, int N) {
    int i = blockIdx.x * 256 + threadIdx.x;
    if (i >= N) return;
    float di = dinv[i];
    const float2* xr = reinterpret_cast<const float2*>(x + (size_t)i * IN_DIM);
    float2 t0 = xr[0], t1 = xr[1], t2 = xr[2], t3 = xr[3], t4 = xr[4];
    float4* op = reinterpret_cast<float4*>(xp + ((size_t)i << 4));
    op[0] = make_float4(t0.x * di, t0.y * di, t1.x * di, t1.y * di);
    op[1] = make_float4(t2.x * di, t2.y * di, t3.x * di, t3.y * di);
    op[2] = make_float4(t4.x * di, t4.y * di, 0.0f, 0.0f);
    op[3] = make_float4(0.0f, 0.0f, 0.0f, 0.0f);
}

// ---------------- layer-1: register gather (1 line/edge, unroll-2) + MLP ------
__global__ __launch_bounds__(1024) void gather1_kernel(
        const int* __restrict__ csr, const unsigned* __restrict__ rowstart,
        const float* __restrict__ xp, const float* __restrict__ dinv,
        const float* __restrict__ W1, const float* __restrict__ b1,
        const float* __restrict__ W2, float2* __restrict__ ts, int N) {
    __shared__ float sW1[IN_DIM * HID_DIM];
    __shared__ float sb1[HID_DIM];
    __shared__ float sW2[HID_DIM * OUT_DIM];
    int t = threadIdx.x;
    for (int k = t; k < IN_DIM * HID_DIM; k += 1024) sW1[k] = W1[k];
    if (t < HID_DIM) sb1[t] = b1[t];
    if (t < HID_DIM * OUT_DIM) sW2[t] = W2[t];
    __syncthreads();

    int i = blockIdx.x * 1024 + t;
    if (i >= N) return;
    unsigned e = rowstart[i], end = rowstart[i + 1];
    float v[IN_DIM];
    {
        const float4* xi = reinterpret_cast<const float4*>(xp + ((size_t)i << 4));
        float4 a = xi[0], b = xi[1];
        float2 c = reinterpret_cast<const float2*>(xi)[4];
        v[0] = a.x; v[1] = a.y; v[2] = a.z; v[3] = a.w;
        v[4] = b.x; v[5] = b.y; v[6] = b.z; v[7] = b.w;
        v[8] = c.x; v[9] = c.y;
    }
    while (e + 1 < end) {  // two independent gathers in flight
        int s0 = csr[e], s1 = csr[e + 1];
        const float4* r0 = reinterpret_cast<const float4*>(xp + ((size_t)s0 << 4));
        const float4* r1 = reinterpret_cast<const float4*>(xp + ((size_t)s1 << 4));
        float4 a0 = r0[0], q0 = r0[1];
        float2 c0 = reinterpret_cast<const float2*>(r0)[4];
        float4 a1 = r1[0], q1 = r1[1];
        float2 c1 = reinterpret_cast<const float2*>(r1)[4];
        v[0] += a0.x + a1.x; v[1] += a0.y + a1.y; v[2] += a0.z + a1.z; v[3] += a0.w + a1.w;
        v[4] += q0.x + q1.x; v[5] += q0.y + q1.y; v[6] += q0.z + q1.z; v[7] += q0.w + q1.w;
        v[8] += c0.x + c1.x; v[9] += c0.y + c1.y;
        e += 2;
    }
    if (e < end) {
        int s = csr[e];
        const float4* r = reinterpret_cast<const float4*>(xp + ((size_t)s << 4));
        float4 a = r[0], q = r[1];
        float2 c = reinterpret_cast<const float2*>(r)[4];
        v[0] += a.x; v[1] += a.y; v[2] += a.z; v[3] += a.w;
        v[4] += q.x; v[5] += q.y; v[6] += q.z; v[7] += q.w;
        v[8] += c.x; v[9] += c.y;
    }
    float di = dinv[i];
    #pragma unroll
    for (int k = 0; k < IN_DIM; ++k) v[k] *= di;
    float t0 = 0.0f, t1 = 0.0f;
    #pragma unroll
    for (int j = 0; j < HID_DIM; ++j) {
        float hh = sb1[j];
        #pragma unroll
        for (int q = 0; q < IN_DIM; ++q) hh = fmaf(v[q], sW1[q * HID_DIM + j], hh);
        hh = fmaxf(hh, 0.0f);
        t0 = fmaf(hh, sW2[2 * j + 0], t0);
        t1 = fmaf(hh, sW2[2 * j + 1], t1);
    }
    ts[i] = make_float2(t0 * di, t1 * di);
}

// ---------------- layer-2: register gather (unroll-2) + log_softmax -----------
__global__ __launch_bounds__(256) void gather2_kernel(
        const int* __restrict__ csr, const unsigned* __restrict__ rowstart,
        const float2* __restrict__ ts, const float* __restrict__ dinv,
        const float* __restrict__ b2, float2* __restrict__ out, int N) {
    int i = blockIdx.x * 256 + threadIdx.x;
    if (i >= N) return;
    unsigned e = rowstart[i], end = rowstart[i + 1];
    float2 acc = ts[i];  // self-loop (already carries dinv[i] factor)
    while (e + 1 < end) {
        int s0 = csr[e], s1 = csr[e + 1];
        float2 t0 = ts[s0], t1 = ts[s1];
        acc.x += t0.x + t1.x; acc.y += t0.y + t1.y;
        e += 2;
    }
    if (e < end) {
        float2 tv = ts[csr[e]];
        acc.x += tv.x; acc.y += tv.y;
    }
    float di = dinv[i];
    float a0 = di * acc.x + b2[0];
    float a1 = di * acc.y + b2[1];
    float m = fmaxf(a0, a1);
    float lse = m + logf(expf(a0 - m) + expf(a1 - m));
    out[i] = make_float2(a0 - lse, a1 - lse);
}

extern "C" void kernel_launch(void* const* d_in, const int* in_sizes, int n_in,
                              void* d_out, int out_size, void* d_ws, size_t ws_size,
                              hipStream_t stream) {
    const float* x  = (const float*)d_in[0];
    const int*   ei = (const int*)d_in[1];   // [2, E]: src row then dst row
    const float* W1 = (const float*)d_in[2];
    const float* b1 = (const float*)d_in[3];
    const float* W2 = (const float*)d_in[4];
    const float* b2 = (const float*)d_in[5];
    float2* out = (float2*)d_out;

    const int* src = ei;
    const int* dst = ei + N_EDGES;

    // workspace (4B elems): bcount[256] | bbase[257] | bcursor[256] |
    // rowstart[N+1] | dinv[N] | ts[2N] | packed[8M] | csr[8M]   ~= 69 MB
    // xp (500K x 16 floats = 8M) ALIASES packed (dead after csrbuild).
    unsigned* bcount   = (unsigned*)d_ws;
    unsigned* bbase    = bcount + NBP;
    unsigned* bcursor  = bbase + NBP + 1;
    unsigned* rowstart = bcursor + NBP;
    float*    dinv     = (float*)(rowstart + N_NODES + 1);
    float2*   ts       = (float2*)(dinv + N_NODES);
    unsigned* packed   = (unsigned*)(ts + N_NODES);
    int*      csr      = (int*)(packed + N_EDGES);
    float*    xp       = (float*)packed;     // reuse after csrbuild

    zero_small_kernel<<<1, NBP, 0, stream>>>(bcount);
    hist_kernel<<<1024, NBP, 0, stream>>>((const int4*)dst, bcount, N_EDGES / 4);
    scan_kernel<<<1, NBP, 0, stream>>>(bcount, bbase, bcursor, rowstart);
    partition_kernel<<<NTILES, PART_TPB, 0, stream>>>(src, dst, bcursor, packed, N_EDGES);
    csrbuild_kernel<<<NB, 1024, 0, stream>>>(packed, bbase, rowstart, csr, dinv, N_NODES);
    padx_kernel<<<(N_NODES + 255) / 256, 256, 0, stream>>>(x, dinv, xp, N_NODES);
    gather1_kernel<<<(N_NODES + 1023) / 1024, 1024, 0, stream>>>(csr, rowstart, xp, dinv, W1, b1, W2, ts, N_NODES);
    gather2_kernel<<<(N_NODES + 255) / 256, 256, 0, stream>>>(csr, rowstart, ts, dinv, b2, out, N_NODES);
}